// Round 1
// baseline (390.910 us; speedup 1.0000x reference)
//
#include <hip/hip_runtime.h>

#define TSTEPS 128
#define NIN 24
#define HD 128
#define NG 512
#define BT 16
#define NBLK 128     // 2048 / BT
#define NTH 512

#define S0 168       // layer-0 A-panel row stride (f16 elems): 0..23 x | 24..31 zero | 32..159 h
#define S1 264       // layer-1 A-panel row stride: 0..127 h1_t | 128..255 h2_prev
#define X0COLS 32
#define H1COL 128

typedef _Float16 half8  __attribute__((ext_vector_type(8)));
typedef _Float16 half4v __attribute__((ext_vector_type(4)));
typedef float    floatx4 __attribute__((ext_vector_type(4)));

__device__ __forceinline__ float sigf(float x) {
    return __builtin_amdgcn_rcpf(1.0f + __expf(-x));
}
__device__ __forceinline__ float tanh_f(float x) {
    // tanh(x) = 1 - 2/(e^{2x}+1); saturates correctly at +-inf
    return 1.0f - 2.0f * __builtin_amdgcn_rcpf(1.0f + __expf(2.0f * x));
}

// load 8 consecutive fp32 and convert to a f16 MFMA fragment (4 VGPRs)
__device__ __forceinline__ half8 ldw8(const float* p) {
    const float4* q = (const float4*)p;
    float4 a = q[0], b = q[1];
    half8 r;
    r[0] = (_Float16)a.x; r[1] = (_Float16)a.y; r[2] = (_Float16)a.z; r[3] = (_Float16)a.w;
    r[4] = (_Float16)b.x; r[5] = (_Float16)b.y; r[6] = (_Float16)b.z; r[7] = (_Float16)b.w;
    return r;
}

__global__ __launch_bounds__(NTH, 2)
void lstm2_fused(const float* __restrict__ x,
                 const float* __restrict__ Wih0, const float* __restrict__ Whh0,
                 const float* __restrict__ bih0, const float* __restrict__ bhh0,
                 const float* __restrict__ Wih1, const float* __restrict__ Whh1,
                 const float* __restrict__ bih1, const float* __restrict__ bhh1,
                 const float* __restrict__ Wfc,  const float* __restrict__ bfc,
                 float* __restrict__ out, _Float16* __restrict__ h1ws)
{
    __shared__ _Float16 A0[2][BT * S0];
    __shared__ _Float16 A1[2][BT * S1];

    const int tid = threadIdx.x;
    const int blk = blockIdx.x;
    const int wv  = tid >> 6;       // wave 0..7
    const int ln  = tid & 63;
    const int qd  = ln >> 4;        // quad 0..3
    const int nn  = ln & 15;
    const int b0  = blk * BT;

    // ---- zero LDS (x pad cols stay zero forever; h regions = initial h=0) ----
    for (int i = tid; i < BT * S0; i += NTH) { A0[0][i] = (_Float16)0.f; A0[1][i] = (_Float16)0.f; }
    for (int i = tid; i < BT * S1; i += NTH) { A1[0][i] = (_Float16)0.f; A1[1][i] = (_Float16)0.f; }

    // combined biases, one fp32 per lane per gate-tile (i,f,g,o)
    float bias0[4], bias1[4];
#pragma unroll
    for (int tI = 0; tI < 4; ++tI) {
        int g = tI * HD + wv * 16 + nn;
        bias0[tI] = bih0[g] + bhh0[g];
        bias1[tI] = bih1[g] + bhh1[g];
    }

    // ---- phase A weights: B-frag = W[g0+nn][kk*32 + qd*8 + j] ----
    half8 w0[4][5];
#pragma unroll
    for (int tI = 0; tI < 4; ++tI) {
        int g = tI * HD + wv * 16 + nn;
        if (qd < 3) w0[tI][0] = ldw8(Wih0 + g * NIN + qd * 8);   // k 0..23 (24 = 3*8)
        else        { half8 z = {0,0,0,0,0,0,0,0}; w0[tI][0] = z; } // zero-pad k 24..31
#pragma unroll
        for (int kk = 1; kk < 5; ++kk)
            w0[tI][kk] = ldw8(Whh0 + g * HD + (kk - 1) * 32 + qd * 8);
    }

    __syncthreads();   // zero-init visible before x staging

    // stage x_0 into A0[0] cols 0..23
    if (tid < BT * NIN) {
        int m = tid / NIN, c = tid % NIN;
        A0[0][m * S0 + c] = (_Float16)x[(size_t)(b0 + m) * (TSTEPS * NIN) + c];
    }

    float cs[4] = {0.f, 0.f, 0.f, 0.f};

    // =============== phase A: layer 0 ===============
#pragma unroll 1
    for (int t = 0; t < TSTEPS; ++t) {
        const int cur = t & 1, nxt = cur ^ 1;
        __syncthreads();              // A0[cur] fully staged (x_t + h_{t-1})

        // coalesced store of h1_{t-1} (completed last step) to workspace
        if (t > 0) {
            int m = tid >> 5, c4 = (tid & 31) * 4;
            half4v v = *(const half4v*)&A0[cur][m * S0 + X0COLS + c4];
            *(half4v*)(h1ws + ((size_t)((t - 1) * NBLK + blk) * BT + m) * HD + c4) = v;
        }
        // stage x_{t+1} into the other buffer (no reader until next barrier)
        if (t + 1 < TSTEPS && tid < BT * NIN) {
            int m = tid / NIN, c = tid % NIN;
            A0[nxt][m * S0 + c] = (_Float16)x[(size_t)(b0 + m) * (TSTEPS * NIN) + (t + 1) * NIN + c];
        }

        // A-fragments: lane = batch row nn, k = kk*32 + qd*8 .. +8  (ds_read_b128)
        half8 af[5];
#pragma unroll
        for (int kk = 0; kk < 5; ++kk)
            af[kk] = *(const half8*)&A0[cur][nn * S0 + kk * 32 + qd * 8];

        floatx4 acc[4];
#pragma unroll
        for (int tI = 0; tI < 4; ++tI) {
            floatx4 a = {bias0[tI], bias0[tI], bias0[tI], bias0[tI]};
#pragma unroll
            for (int kk = 0; kk < 5; ++kk)
                a = __builtin_amdgcn_mfma_f32_16x16x32_f16(af[kk], w0[tI][kk], a, 0, 0, 0);
            acc[tI] = a;
        }

        // epilogue: lane owns h-index jc for batches m = qd*4 + r
        const int jc = X0COLS + wv * 16 + nn;
#pragma unroll
        for (int r = 0; r < 4; ++r) {
            float iv = sigf(acc[0][r]);
            float fv = sigf(acc[1][r]);
            float gv = tanh_f(acc[2][r]);
            float ov = sigf(acc[3][r]);
            float cn = fv * cs[r] + iv * gv;
            cs[r] = cn;
            float hv = ov * tanh_f(cn);
            A0[nxt][(qd * 4 + r) * S0 + jc] = (_Float16)hv;
        }
    }
    __syncthreads();
    {   // final h1_127 is in A0[0]
        int m = tid >> 5, c4 = (tid & 31) * 4;
        half4v v = *(const half4v*)&A0[0][m * S0 + X0COLS + c4];
        *(half4v*)(h1ws + ((size_t)(127 * NBLK + blk) * BT + m) * HD + c4) = v;
    }

    // =============== phase B: layer 1 ===============
    half8 w1[4][8];
#pragma unroll
    for (int tI = 0; tI < 4; ++tI) {
        int g = tI * HD + wv * 16 + nn;
#pragma unroll
        for (int kk = 0; kk < 4; ++kk)
            w1[tI][kk] = ldw8(Wih1 + g * HD + kk * 32 + qd * 8);
#pragma unroll
        for (int kk = 4; kk < 8; ++kk)
            w1[tI][kk] = ldw8(Whh1 + g * HD + (kk - 4) * 32 + qd * 8);
    }
    {   // stage h1_0 into A1[0] cols 0..127
        int m = tid >> 5, c4 = (tid & 31) * 4;
        half4v v = *(const half4v*)(h1ws + ((size_t)blk * BT + m) * HD + c4);
        *(half4v*)&A1[0][m * S1 + c4] = v;
    }
    float cs1[4] = {0.f, 0.f, 0.f, 0.f};

#pragma unroll 1
    for (int t = 0; t < TSTEPS; ++t) {
        const int cur = t & 1, nxt = cur ^ 1;
        __syncthreads();              // A1[cur] staged (h1_t + h2_{t-1})

        // prefetch h1_{t+1} from ws (global load overlaps MFMAs; LDS write at end)
        int m = tid >> 5, c4 = (tid & 31) * 4;
        half4v pre;
        if (t + 1 < TSTEPS)
            pre = *(const half4v*)(h1ws + ((size_t)((t + 1) * NBLK + blk) * BT + m) * HD + c4);

        half8 af[8];
#pragma unroll
        for (int kk = 0; kk < 8; ++kk)
            af[kk] = *(const half8*)&A1[cur][nn * S1 + kk * 32 + qd * 8];

        floatx4 acc[4];
#pragma unroll
        for (int tI = 0; tI < 4; ++tI) {
            floatx4 a = {bias1[tI], bias1[tI], bias1[tI], bias1[tI]};
#pragma unroll
            for (int kk = 0; kk < 8; ++kk)
                a = __builtin_amdgcn_mfma_f32_16x16x32_f16(af[kk], w1[tI][kk], a, 0, 0, 0);
            acc[tI] = a;
        }

        const int jc = H1COL + wv * 16 + nn;
#pragma unroll
        for (int r = 0; r < 4; ++r) {
            float iv = sigf(acc[0][r]);
            float fv = sigf(acc[1][r]);
            float gv = tanh_f(acc[2][r]);
            float ov = sigf(acc[3][r]);
            float cn = fv * cs1[r] + iv * gv;
            cs1[r] = cn;
            float hv = ov * tanh_f(cn);
            A1[nxt][(qd * 4 + r) * S1 + jc] = (_Float16)hv;
        }
        if (t + 1 < TSTEPS)
            *(half4v*)&A1[nxt][m * S1 + c4] = pre;
    }
    __syncthreads();

    // =============== FC head: out[b] = h2_127[b,:] . Wfc + bfc ===============
    {
        int b = tid >> 5, sub = tid & 31;
        const _Float16* hp = &A1[0][b * S1 + H1COL + sub * 4];
        const float4 wv4 = *(const float4*)(Wfc + sub * 4);
        float s = (float)hp[0] * wv4.x + (float)hp[1] * wv4.y
                + (float)hp[2] * wv4.z + (float)hp[3] * wv4.w;
        s += __shfl_down(s, 16, 32);
        s += __shfl_down(s, 8, 32);
        s += __shfl_down(s, 4, 32);
        s += __shfl_down(s, 2, 32);
        s += __shfl_down(s, 1, 32);
        if (sub == 0) out[b0 + b] = s + bfc[0];
    }
}

extern "C" void kernel_launch(void* const* d_in, const int* in_sizes, int n_in,
                              void* d_out, int out_size, void* d_ws, size_t ws_size,
                              hipStream_t stream) {
    const float* x    = (const float*)d_in[0];
    const float* Wih0 = (const float*)d_in[1];
    const float* Whh0 = (const float*)d_in[2];
    const float* bih0 = (const float*)d_in[3];
    const float* bhh0 = (const float*)d_in[4];
    const float* Wih1 = (const float*)d_in[5];
    const float* Whh1 = (const float*)d_in[6];
    const float* bih1 = (const float*)d_in[7];
    const float* bhh1 = (const float*)d_in[8];
    const float* Wfc  = (const float*)d_in[9];
    const float* bfc  = (const float*)d_in[10];
    float* out = (float*)d_out;
    _Float16* h1ws = (_Float16*)d_ws;   // [T][NBLK][BT][HD] f16 = 64 MB

    lstm2_fused<<<dim3(NBLK), dim3(NTH), 0, stream>>>(
        x, Wih0, Whh0, bih0, bhh0, Wih1, Whh1, bih1, bhh1, Wfc, bfc, out, h1ws);
}

// Round 2
// 371.540 us; speedup vs baseline: 1.0521x; 1.0521x over previous
//
#include <hip/hip_runtime.h>

#define TSTEPS 128
#define NIN 24
#define HD 128
#define BT 16
#define NBLK 128     // 2048 / BT
#define NTH 512

// LDS geometry (units: _Float16 elements)
#define RS    136               // h-panel row stride: 16B-aligned rows, bank-balanced
#define SLOT  (BT*RS)           // 2176
#define XS    40                // x row stride (16B-aligned, 2-way bank alias only)
#define XTS   (BT*XS)           // 640 per timestep
#define XBUF  (8*XTS)           // 5120 per chunk buffer
#define RINGN 9                 // 9-slot ring: dump slots disjoint from same-step write

#define RING_OFF 0                       // 9*2176 = 19584
#define XB_OFF   (RINGN*SLOT)            // 19584
#define SM_SIZE  (XB_OFF + 2*XBUF)       // 29824 f16 = 59648 B  (< 64 KB)

// phase-B overlay of the same LDS
#define HB_OFF 0                         // [2][4][SLOT] = 17408
#define B2_OFF (8*SLOT)                  // 17408 ; [2][SLOT] = 4352

typedef _Float16 half8  __attribute__((ext_vector_type(8)));
typedef _Float16 half4v __attribute__((ext_vector_type(4)));
typedef float    floatx4 __attribute__((ext_vector_type(4)));

__device__ __forceinline__ float sigf(float x) {
    return __builtin_amdgcn_rcpf(1.0f + __expf(-x));
}
__device__ __forceinline__ float tanh_f(float x) {
    return 1.0f - 2.0f * __builtin_amdgcn_rcpf(1.0f + __expf(2.0f * x));
}

__device__ __forceinline__ half8 ldw8(const float* p) {
    const float4* q = (const float4*)p;
    float4 a = q[0], b = q[1];
    half8 r;
    r[0] = (_Float16)a.x; r[1] = (_Float16)a.y; r[2] = (_Float16)a.z; r[3] = (_Float16)a.w;
    r[4] = (_Float16)b.x; r[5] = (_Float16)b.y; r[6] = (_Float16)b.z; r[7] = (_Float16)b.w;
    return r;
}

__global__ __launch_bounds__(NTH, 2)
void lstm2_fused(const float* __restrict__ x,
                 const float* __restrict__ Wih0, const float* __restrict__ Whh0,
                 const float* __restrict__ bih0, const float* __restrict__ bhh0,
                 const float* __restrict__ Wih1, const float* __restrict__ Whh1,
                 const float* __restrict__ bih1, const float* __restrict__ bhh1,
                 const float* __restrict__ Wfc,  const float* __restrict__ bfc,
                 float* __restrict__ out, _Float16* __restrict__ h1ws)
{
    __shared__ __align__(16) _Float16 SM[SM_SIZE];

    const int tid = threadIdx.x;
    const int blk = blockIdx.x;
    const int wv  = tid >> 6;
    const int ln  = tid & 63;
    const int qd  = ln >> 4;
    const int nn  = ln & 15;
    const int b0  = blk * BT;
    const size_t wsbase = (size_t)blk * (TSTEPS * BT * HD);   // f16 units

    const half8 z8 = {0, 0, 0, 0, 0, 0, 0, 0};

    // ---- zero all LDS (ring slots = h1 init 0; x pad cols stay 0 forever) ----
    for (int i = tid * 8; i < SM_SIZE; i += NTH * 8) *(half8*)&SM[i] = z8;

    // combined biases
    float bias0[4], bias1[4];
#pragma unroll
    for (int tI = 0; tI < 4; ++tI) {
        int g = tI * HD + wv * 16 + nn;
        bias0[tI] = bih0[g] + bhh0[g];
        bias1[tI] = bih1[g] + bhh1[g];
    }

    // ---- phase A weights ----
    half8 wih0[4];
    half8 whh0[4][4];
#pragma unroll
    for (int tI = 0; tI < 4; ++tI) {
        int g = tI * HD + wv * 16 + nn;
        if (qd < 3) wih0[tI] = ldw8(Wih0 + g * NIN + qd * 8);
        else        wih0[tI] = z8;
#pragma unroll
        for (int kk = 0; kk < 4; ++kk)
            whh0[tI][kk] = ldw8(Whh0 + g * HD + kk * 32 + qd * 8);
    }

    __syncthreads();   // zero-init visible

    // ---- stage x chunk 0 into xb buf 0 ----
    {
        const int c = 0, buf = 0;
        for (int i = tid; i < 8 * BT * 6; i += NTH) {
            int ti = i / 96, r = i % 96, b = r / 6, q = r % 6;
            float4 v = *(const float4*)(x + (size_t)(b0 + b) * (TSTEPS * NIN)
                                          + (size_t)(c * 8 + ti) * NIN + q * 4);
            half4v h; h[0] = (_Float16)v.x; h[1] = (_Float16)v.y;
                      h[2] = (_Float16)v.z; h[3] = (_Float16)v.w;
            *(half4v*)&SM[XB_OFF + buf * XBUF + ti * XTS + b * XS + q * 4] = h;
        }
    }

    float cs0[4] = {0.f, 0.f, 0.f, 0.f};
    const int jc = wv * 16 + nn;

    // =============== phase A: layer 0, 128 steps, no per-step global ops ===============
#pragma unroll 1
    for (int t = 0; t < TSTEPS; ++t) {
        __syncthreads();              // ring slot (t-1)%9 + x chunk for t visible

        if ((t & 7) == 0) {
            // stage x chunk t/8+1 (consumed from step t+8)
            if (t + 8 < TSTEPS) {
                const int c = (t >> 3) + 1, buf = c & 1;
                for (int i = tid; i < 8 * BT * 6; i += NTH) {
                    int ti = i / 96, r = i % 96, b = r / 6, q = r % 6;
                    float4 v = *(const float4*)(x + (size_t)(b0 + b) * (TSTEPS * NIN)
                                                  + (size_t)(c * 8 + ti) * NIN + q * 4);
                    half4v h; h[0] = (_Float16)v.x; h[1] = (_Float16)v.y;
                              h[2] = (_Float16)v.z; h[3] = (_Float16)v.w;
                    *(half4v*)&SM[XB_OFF + buf * XBUF + ti * XTS + b * XS + q * 4] = h;
                }
            }
            // dump chunk (t/8 - 1): times t-8..t-1; slots != t%9, no race with epilogue
            if (t > 0) {
                const int c = (t >> 3) - 1;
#pragma unroll
                for (int k = 0; k < 4; ++k) {
                    int e  = tid + k * NTH;        // 0..2047 b128-units
                    int ti = e >> 8;
                    int r  = e & 255;
                    int b  = r >> 4;
                    int c8 = (r & 15) * 8;
                    int tau = c * 8 + ti;
                    half8 v = *(const half8*)&SM[RING_OFF + (tau % 9) * SLOT + b * RS + c8];
                    *(half8*)(h1ws + wsbase + ((size_t)tau * BT + b) * HD + c8) = v;
                }
            }
        }

        // A-fragments
        const half8 ax = *(const half8*)&SM[XB_OFF + ((t >> 3) & 1) * XBUF
                                            + (t & 7) * XTS + nn * XS + qd * 8];
        const int sprev = (t + 8) % 9;
        half8 ah[4];
#pragma unroll
        for (int kk = 0; kk < 4; ++kk)
            ah[kk] = *(const half8*)&SM[RING_OFF + sprev * SLOT + nn * RS + kk * 32 + qd * 8];

        floatx4 acc[4];
#pragma unroll
        for (int tI = 0; tI < 4; ++tI) {
            floatx4 a = {bias0[tI], bias0[tI], bias0[tI], bias0[tI]};
            a = __builtin_amdgcn_mfma_f32_16x16x32_f16(ax, wih0[tI], a, 0, 0, 0);
#pragma unroll
            for (int kk = 0; kk < 4; ++kk)
                a = __builtin_amdgcn_mfma_f32_16x16x32_f16(ah[kk], whh0[tI][kk], a, 0, 0, 0);
            acc[tI] = a;
        }

        const int scur = t % 9;
#pragma unroll
        for (int r = 0; r < 4; ++r) {
            float iv = sigf(acc[0][r]);
            float fv = sigf(acc[1][r]);
            float gv = tanh_f(acc[2][r]);
            float ov = sigf(acc[3][r]);
            float cn = fv * cs0[r] + iv * gv;
            cs0[r] = cn;
            float hv = ov * tanh_f(cn);
            SM[RING_OFF + scur * SLOT + (qd * 4 + r) * RS + jc] = (_Float16)hv;
        }
    }

    __syncthreads();
    // dump final chunk 15 (times 120..127)
    {
        const int c = 15;
#pragma unroll
        for (int k = 0; k < 4; ++k) {
            int e  = tid + k * NTH;
            int ti = e >> 8;
            int r  = e & 255;
            int b  = r >> 4;
            int c8 = (r & 15) * 8;
            int tau = c * 8 + ti;
            half8 v = *(const half8*)&SM[RING_OFF + (tau % 9) * SLOT + b * RS + c8];
            *(half8*)(h1ws + wsbase + ((size_t)tau * BT + b) * HD + c8) = v;
        }
    }

    // ---- phase B weights (phase A regs dead, allocator reuses) ----
    half8 wih1[4][4], whh1[4][4];
#pragma unroll
    for (int tI = 0; tI < 4; ++tI) {
        int g = tI * HD + wv * 16 + nn;
#pragma unroll
        for (int kk = 0; kk < 4; ++kk) {
            wih1[tI][kk] = ldw8(Wih1 + g * HD + kk * 32 + qd * 8);
            whh1[tI][kk] = ldw8(Whh1 + g * HD + kk * 32 + qd * 8);
        }
    }

    __syncthreads();   // all dump ds_reads of ring done before overlay reuse

    // zero b2 (h2 init 0), preload hb chunk 0 (h1ws chunk 0 stores drained long ago)
    for (int i = tid * 8; i < 2 * SLOT; i += NTH * 8) *(half8*)&SM[B2_OFF + i] = z8;
    {
        const int c = 0, buf = 0;
#pragma unroll
        for (int k = 0; k < 2; ++k) {
            int e  = tid + k * NTH;     // 0..1023
            int ti = e >> 8;
            int r  = e & 255;
            int b  = r >> 4;
            int c8 = (r & 15) * 8;
            half8 v = *(const half8*)(h1ws + wsbase + ((size_t)(c * 4 + ti) * BT + b) * HD + c8);
            *(half8*)&SM[HB_OFF + buf * (4 * SLOT) + ti * SLOT + b * RS + c8] = v;
        }
    }

    float cs1[4] = {0.f, 0.f, 0.f, 0.f};

    // =============== phase B: layer 1, 128 steps ===============
#pragma unroll 1
    for (int tau = 0; tau < TSTEPS; ++tau) {
        __syncthreads();

        if ((tau & 3) == 0 && tau + 4 < TSTEPS) {
            const int c = (tau >> 2) + 1, buf = c & 1;
#pragma unroll
            for (int k = 0; k < 2; ++k) {
                int e  = tid + k * NTH;
                int ti = e >> 8;
                int r  = e & 255;
                int b  = r >> 4;
                int c8 = (r & 15) * 8;
                half8 v = *(const half8*)(h1ws + wsbase + ((size_t)(c * 4 + ti) * BT + b) * HD + c8);
                *(half8*)&SM[HB_OFF + buf * (4 * SLOT) + ti * SLOT + b * RS + c8] = v;
            }
        }

        const int cur = tau & 1, nxt = cur ^ 1;
        const int hbase = HB_OFF + ((tau >> 2) & 1) * (4 * SLOT) + (tau & 3) * SLOT;

        half8 a1[4], a2[4];
#pragma unroll
        for (int kk = 0; kk < 4; ++kk) {
            a1[kk] = *(const half8*)&SM[hbase + nn * RS + kk * 32 + qd * 8];
            a2[kk] = *(const half8*)&SM[B2_OFF + cur * SLOT + nn * RS + kk * 32 + qd * 8];
        }

        floatx4 acc[4];
#pragma unroll
        for (int tI = 0; tI < 4; ++tI) {
            floatx4 a = {bias1[tI], bias1[tI], bias1[tI], bias1[tI]};
#pragma unroll
            for (int kk = 0; kk < 4; ++kk)
                a = __builtin_amdgcn_mfma_f32_16x16x32_f16(a1[kk], wih1[tI][kk], a, 0, 0, 0);
#pragma unroll
            for (int kk = 0; kk < 4; ++kk)
                a = __builtin_amdgcn_mfma_f32_16x16x32_f16(a2[kk], whh1[tI][kk], a, 0, 0, 0);
            acc[tI] = a;
        }

#pragma unroll
        for (int r = 0; r < 4; ++r) {
            float iv = sigf(acc[0][r]);
            float fv = sigf(acc[1][r]);
            float gv = tanh_f(acc[2][r]);
            float ov = sigf(acc[3][r]);
            float cn = fv * cs1[r] + iv * gv;
            cs1[r] = cn;
            float hv = ov * tanh_f(cn);
            SM[B2_OFF + nxt * SLOT + (qd * 4 + r) * RS + jc] = (_Float16)hv;
        }
    }
    __syncthreads();

    // =============== FC head: h2_127 is in b2[0] ===============
    {
        int b = tid >> 5, sub = tid & 31;
        const _Float16* hp = &SM[B2_OFF + b * RS + sub * 4];
        const float4 wv4 = *(const float4*)(Wfc + sub * 4);
        float s = (float)hp[0] * wv4.x + (float)hp[1] * wv4.y
                + (float)hp[2] * wv4.z + (float)hp[3] * wv4.w;
        s += __shfl_down(s, 16, 32);
        s += __shfl_down(s, 8, 32);
        s += __shfl_down(s, 4, 32);
        s += __shfl_down(s, 2, 32);
        s += __shfl_down(s, 1, 32);
        if (sub == 0) out[b0 + b] = s + bfc[0];
    }
}

extern "C" void kernel_launch(void* const* d_in, const int* in_sizes, int n_in,
                              void* d_out, int out_size, void* d_ws, size_t ws_size,
                              hipStream_t stream) {
    const float* x    = (const float*)d_in[0];
    const float* Wih0 = (const float*)d_in[1];
    const float* Whh0 = (const float*)d_in[2];
    const float* bih0 = (const float*)d_in[3];
    const float* bhh0 = (const float*)d_in[4];
    const float* Wih1 = (const float*)d_in[5];
    const float* Whh1 = (const float*)d_in[6];
    const float* bih1 = (const float*)d_in[7];
    const float* bhh1 = (const float*)d_in[8];
    const float* Wfc  = (const float*)d_in[9];
    const float* bfc  = (const float*)d_in[10];
    float* out = (float*)d_out;
    _Float16* h1ws = (_Float16*)d_ws;   // [NBLK][T][BT][HD] f16 = 64 MB

    lstm2_fused<<<dim3(NBLK), dim3(NTH), 0, stream>>>(
        x, Wih0, Whh0, bih0, bhh0, Wih1, Whh1, bih1, bhh1, Wfc, bfc, out, h1ws);
}